// Round 1
// baseline (1076.514 us; speedup 1.0000x reference)
//
#include <hip/hip_runtime.h>

#define H 4096
#define W 4096
#define KH 31
#define KW 31
#define OH (H - KH + 1)   // 4066
#define OW (W - KW + 1)   // 4066
#define BT 64             // output tile edge
#define IT (BT + KW - 1)  // 94 input tile edge
#define XS_STRIDE 96      // padded LDS row stride (floats), 16B-aligned rows

__global__ __launch_bounds__(256, 2)
void conv2d_direct_f32(const float* __restrict__ X,
                       const float* __restrict__ Kf,
                       float* __restrict__ out) {
    __shared__ float Xs[IT][XS_STRIDE];  // 94*96*4 = 36096 B
    __shared__ float Ks[KH][32];         // 31*32*4 = 3968 B

    const int tid = threadIdx.x;   // 0..255
    const int tx  = tid & 15;      // output col group
    const int ty  = tid >> 4;      // output row group
    const int ox0 = blockIdx.x * BT;
    const int oy0 = blockIdx.y * BT;

    // Stage K into LDS
    for (int i = tid; i < KH * KW; i += 256) {
        Ks[i / KW][i % KW] = Kf[i];
    }
    // Stage X halo tile into LDS (guarded: edge tiles read past 4095)
    for (int i = tid; i < IT * IT; i += 256) {
        const int r = i / IT, c = i % IT;
        const int gy = oy0 + r, gx = ox0 + c;
        float v = 0.0f;
        if (gy < H && gx < W) v = X[gy * W + gx];
        Xs[r][c] = v;
    }
    __syncthreads();

    float acc[4][4] = {};

    for (int dy = 0; dy < KH; ++dy) {
        // Hoist K row into registers (uniform LDS broadcast reads)
        float kr[32];
        #pragma unroll
        for (int s = 0; s < 8; ++s) {
            *reinterpret_cast<float4*>(&kr[s * 4]) =
                *reinterpret_cast<const float4*>(&Ks[dy][s * 4]);
        }
        #pragma unroll
        for (int i = 0; i < 4; ++i) {
            const int row = ty * 4 + i + dy;  // ≤ 60+3+30 = 93
            // 36-float sliding window, 9 x ds_read_b128 (16B-aligned)
            float w[36];
            #pragma unroll
            for (int s = 0; s < 9; ++s) {
                *reinterpret_cast<float4*>(&w[s * 4]) =
                    *reinterpret_cast<const float4*>(&Xs[row][tx * 4 + s * 4]);
            }
            #pragma unroll
            for (int dx = 0; dx < KW; ++dx) {
                #pragma unroll
                for (int j = 0; j < 4; ++j) {
                    acc[i][j] += kr[dx] * w[dx + j];  // static indices -> registers
                }
            }
        }
    }

    // Store 4x4 register tile (guarded at right/bottom edges)
    #pragma unroll
    for (int i = 0; i < 4; ++i) {
        const int oy = oy0 + ty * 4 + i;
        if (oy >= OH) continue;
        #pragma unroll
        for (int j = 0; j < 4; ++j) {
            const int ox = ox0 + tx * 4 + j;
            if (ox < OW) out[oy * OW + ox] = acc[i][j];
        }
    }
}

extern "C" void kernel_launch(void* const* d_in, const int* in_sizes, int n_in,
                              void* d_out, int out_size, void* d_ws, size_t ws_size,
                              hipStream_t stream) {
    const float* X  = (const float*)d_in[0];
    const float* Kf = (const float*)d_in[1];
    float* out = (float*)d_out;

    dim3 grid((OW + BT - 1) / BT, (OH + BT - 1) / BT);  // 64 x 64
    dim3 block(256);
    conv2d_direct_f32<<<grid, block, 0, stream>>>(X, Kf, out);
}

// Round 2
// 434.627 us; speedup vs baseline: 2.4769x; 2.4769x over previous
//
#include <hip/hip_runtime.h>

#define H 4096
#define W 4096
#define KH 31
#define KW 31
#define OH (H - KH + 1)   // 4066
#define OW (W - KW + 1)   // 4066

#define TR 16             // output tile rows per block
#define TC 256            // output tile cols per block
#define IR (TR + KH - 1)  // 46 input rows
#define ICP 288           // padded input cols (256+30 -> 288, 16B-aligned rows)

__global__ __launch_bounds__(256, 3)
void conv2d_rowreuse_f32(const float* __restrict__ X,
                         const float* __restrict__ Kf,
                         float* __restrict__ out) {
    __shared__ float Xs[IR][ICP];  // 46*288*4 = 52992 B

    const int tid  = threadIdx.x;      // 0..255
    const int lane = tid & 63;         // col group: cols 4*lane .. 4*lane+3
    const int wv   = tid >> 6;         // wave id: out rows 4*wv .. 4*wv+3
    const int ox0  = blockIdx.x * TC;
    const int oy0  = blockIdx.y * TR;

    // ---- Stage input halo tile (46 x 288) as float4, guarded at edges ----
    for (int idx = tid; idx < IR * (ICP / 4); idx += 256) {
        const int r  = idx / (ICP / 4);
        const int c4 = idx % (ICP / 4);
        const int gy = oy0 + r;
        const int gx = ox0 + c4 * 4;
        float4 v = make_float4(0.f, 0.f, 0.f, 0.f);
        if (gy < H) {
            if (gx + 3 < W) {
                v = *reinterpret_cast<const float4*>(X + (size_t)gy * W + gx);
            } else {
                const float* row = X + (size_t)gy * W;
                if (gx + 0 < W) v.x = row[gx + 0];
                if (gx + 1 < W) v.y = row[gx + 1];
                if (gx + 2 < W) v.z = row[gx + 2];
                if (gx + 3 < W) v.w = row[gx + 3];
            }
        }
        *reinterpret_cast<float4*>(&Xs[r][c4 * 4]) = v;
    }
    __syncthreads();

    float acc[4][4] = {};

    // ---- Row-reuse main loop: each input row loaded once per wave ----
    // Wave wv owns output rows (local) 4*wv+0..3; needs input rows 4*wv .. 4*wv+33.
    for (int rr = 0; rr < TR / 4 + KH - 1 + 3; ++rr) {   // 0..33
        const int row = wv * 4 + rr;                     // <= 12+33 = 45 < 46

        // 36-float sliding window: lane-contiguous, wave-uniform row ->
        // conflict-free ds_read_b128 (only w[0..33] are consumed).
        float w[36];
        #pragma unroll
        for (int s = 0; s < 9; ++s) {
            *reinterpret_cast<float4*>(&w[s * 4]) =
                *reinterpret_cast<const float4*>(&Xs[row][lane * 4 + s * 4]);
        }

        #pragma unroll
        for (int i = 0; i < 4; ++i) {
            const int dy = rr - i;             // wave-uniform
            if (dy >= 0 && dy < KH) {          // uniform branch
                const float* kr = Kf + dy * KW;  // uniform -> s_load (SMEM)
                #pragma unroll
                for (int dx = 0; dx < KW; ++dx) {
                    const float k = kr[dx];      // scalar operand
                    #pragma unroll
                    for (int j = 0; j < 4; ++j) {
                        acc[i][j] = fmaf(k, w[dx + j], acc[i][j]);
                    }
                }
            }
        }
    }

    // ---- Store 4 rows x 4 cols, guarded ----
    #pragma unroll
    for (int i = 0; i < 4; ++i) {
        const int oy = oy0 + wv * 4 + i;
        if (oy >= OH) continue;
        float* orow = out + (size_t)oy * OW;
        #pragma unroll
        for (int j = 0; j < 4; ++j) {
            const int ox = ox0 + lane * 4 + j;
            if (ox < OW) orow[ox] = acc[i][j];
        }
    }
}

extern "C" void kernel_launch(void* const* d_in, const int* in_sizes, int n_in,
                              void* d_out, int out_size, void* d_ws, size_t ws_size,
                              hipStream_t stream) {
    const float* X  = (const float*)d_in[0];
    const float* Kf = (const float*)d_in[1];
    float* out = (float*)d_out;

    dim3 grid((OW + TC - 1) / TC, (OH + TR - 1) / TR);  // 16 x 255
    dim3 block(256);
    conv2d_rowreuse_f32<<<grid, block, 0, stream>>>(X, Kf, out);
}

// Round 3
// 97.393 us; speedup vs baseline: 11.0533x; 4.4626x over previous
//
#include <hip/hip_runtime.h>

typedef __attribute__((ext_vector_type(8))) short bf16x8;
typedef __attribute__((ext_vector_type(16))) float f32x16;

#define H 4096
#define W 4096
#define KH 31
#define KW 31
#define OH 4066
#define OW 4066
#define PKROW 104          // padded Toeplitz source row (f32 elems)

#define BROWS 64           // output rows per block
#define BCOLS 256          // output cols per block
#define SROWS 94           // BROWS + KH - 1 staged rows
#define SCOLS 318          // BCOLS + 62 staged cols (used)
#define SPITCH 320         // padded staged cols
#define SPB 640            // bytes per staged row (SPITCH * 2)

// fp32 -> bf16 round-to-nearest-even (bit trick)
__device__ __forceinline__ short bf16rne_s(float f) {
    unsigned u = __builtin_bit_cast(unsigned, f);
    u += 0x7fffu + ((u >> 16) & 1u);
    return (short)(u >> 16);
}

// Pre-kernel: zero-padded Toeplitz source rows PK[dy][p]:
//   PK[dy][KW + d] = K[dy][d] for d in [0,KW), 0 elsewhere.  (13 KB in d_ws)
__global__ void build_pk_kernel(const float* __restrict__ Kf, float* __restrict__ pk) {
    for (int i = threadIdx.x; i < KH * PKROW; i += 256) {
        const int dy = i / PKROW, p = i % PKROW;
        float v = 0.0f;
        if (p >= KW && p < 2 * KW) v = Kf[dy * KW + (p - KW)];
        pk[i] = v;
    }
}

__global__ __launch_bounds__(256, 2)
void conv2d_mfma_bf16(const float* __restrict__ X,
                      const float* __restrict__ pk,
                      float* __restrict__ out) {
    __shared__ unsigned short Xs[SROWS * SPITCH];   // 60160 B, bf16 bits, swizzled
    char* xsb = (char*)Xs;

    const int tid = threadIdx.x;
    const int l   = tid & 63;
    const int lr  = l & 31;       // B col (= y offset) / A row (= x offset) lane index
    const int lh  = l >> 5;       // k-half
    const int wv  = tid >> 6;     // 0..3
    const int wy  = wv >> 1;      // wave row group (0,1)
    const int wx  = wv & 1;       // wave col group (0,1)
    const int by0 = blockIdx.y * BROWS;
    const int bx0 = blockIdx.x * BCOLS;

    // ---------- stage X tile: fp32 -> bf16, XOR-swizzled, once per block ----------
    for (int g = tid; g < SROWS * (SPITCH / 4); g += 256) {
        const int r  = g / (SPITCH / 4);
        const int c0 = (g - r * (SPITCH / 4)) * 4;
        const int gy = by0 + r;
        const int gx = bx0 + c0;
        float4 v = make_float4(0.f, 0.f, 0.f, 0.f);
        if (gy < H && c0 < SCOLS) {
            const float* row = X + (size_t)gy * W;
            if (gx + 3 < W) {
                v = *(const float4*)(row + gx);
            } else {
                if (gx + 0 < W) v.x = row[gx + 0];
                if (gx + 1 < W) v.y = row[gx + 1];
                if (gx + 2 < W) v.z = row[gx + 2];
            }
        }
        ushort4 hh;
        hh.x = (unsigned short)bf16rne_s(v.x);
        hh.y = (unsigned short)bf16rne_s(v.y);
        hh.z = (unsigned short)bf16rne_s(v.z);
        hh.w = (unsigned short)bf16rne_s(v.w);
        const int byte = r * SPB + c0 * 2;
        *(ushort4*)(xsb + (byte ^ ((r & 7) << 4))) = hh;   // swizzle keeps 8B align
    }
    __syncthreads();

    // ---------- main loop: no barriers, LDS read-only ----------
    f32x16 acc[4] = {};

    const int rbase = 32 * wy;        // wave row offset in tile
    const int cbase = 128 * wx;       // wave col offset (elements)

    for (int dy = 0; dy < KH; ++dy) {
        // A-frags: Toeplitz rows from PK (L1-hot global), convert to bf16.
        // element (c,e): K[dy][16c + 8*lh + e - lr], zero outside band.
        bf16x8 a[4];
        const float* pkrow = pk + dy * PKROW + KW + 8 * lh - lr;
        #pragma unroll
        for (int c = 0; c < 4; ++c) {
            float buf[8];
            __builtin_memcpy(buf, pkrow + 16 * c, 32);   // 4B-aligned 32B load
            bf16x8 t;
            #pragma unroll
            for (int e = 0; e < 8; ++e) t[e] = bf16rne_s(buf[e]);
            a[c] = t;
        }

        // B-frags: 10 sliding 16-wide x-chunks; lane = (row lr, k-half lh).
        const int rr = dy + lr + rbase;                  // staged row, <= 93
        const int rowbyte = rr * SPB;
        const int swzmask = (rr & 7) << 4;
        bf16x8 bb[10];
        #pragma unroll
        for (int m = 0; m < 10; ++m) {
            const int byte = rowbyte + (cbase + 16 * m) * 2 + 16 * lh;
            bb[m] = *(const bf16x8*)(xsb + (byte ^ swzmask));   // ds_read_b128
        }

        // 4 tiles x 4 k-chunks; tile t uses chunks 2t..2t+3 (register reuse).
        #pragma unroll
        for (int t = 0; t < 4; ++t) {
            #pragma unroll
            for (int c = 0; c < 4; ++c) {
                acc[t] = __builtin_amdgcn_mfma_f32_32x32x16_bf16(
                             a[c], bb[2 * t + c], acc[t], 0, 0, 0);
            }
        }
    }

    // ---------- epilogue: D row = x-offset = (reg&3)+8*(reg>>2)+4*lh, col = y = lr ----------
    const int oy = by0 + rbase + lr;
    if (oy < OH) {
        float* orow = out + (size_t)oy * OW;
        #pragma unroll
        for (int t = 0; t < 4; ++t) {
            #pragma unroll
            for (int q = 0; q < 4; ++q) {
                const int x = bx0 + cbase + 32 * t + 8 * q + 4 * lh;
                if (x + 3 < OW) {
                    *(float2*)(orow + x)     = make_float2(acc[t][4*q+0], acc[t][4*q+1]);
                    *(float2*)(orow + x + 2) = make_float2(acc[t][4*q+2], acc[t][4*q+3]);
                } else {
                    #pragma unroll
                    for (int e = 0; e < 4; ++e)
                        if (x + e < OW) orow[x + e] = acc[t][4*q+e];
                }
            }
        }
    }
}

extern "C" void kernel_launch(void* const* d_in, const int* in_sizes, int n_in,
                              void* d_out, int out_size, void* d_ws, size_t ws_size,
                              hipStream_t stream) {
    const float* X  = (const float*)d_in[0];
    const float* Kf = (const float*)d_in[1];
    float* out = (float*)d_out;
    float* pk  = (float*)d_ws;    // needs 31*104*4 = 12896 B of scratch

    build_pk_kernel<<<1, 256, 0, stream>>>(Kf, pk);
    dim3 grid((OW + BCOLS - 1) / BCOLS, (OH + BROWS - 1) / BROWS);  // 16 x 64
    conv2d_mfma_bf16<<<grid, dim3(256), 0, stream>>>(X, pk, out);
}

// Round 4
// 91.491 us; speedup vs baseline: 11.7664x; 1.0645x over previous
//
#include <hip/hip_runtime.h>

typedef __attribute__((ext_vector_type(8))) short bf16x8;
typedef __attribute__((ext_vector_type(16))) float f32x16;

#define H 4096
#define W 4096
#define KH 31
#define KW 31
#define OH 4066
#define OW 4066

#define BROWS 32           // output rows per block
#define BCOLS 256          // output cols per block
#define SROWS 62           // BROWS + KH - 1 staged rows
#define SCOLS 318          // BCOLS + 62 staged cols (used)
#define SPITCH 320         // padded staged cols (row = 640 B)
#define SPB 640

// fp32 -> bf16 round-to-nearest-even
__device__ __forceinline__ unsigned short bf16rne_s(float f) {
    unsigned u = __builtin_bit_cast(unsigned, f);
    u += 0x7fffu + ((u >> 16) & 1u);
    return (unsigned short)(u >> 16);
}

// Pre-kernel: bf16 A-frag table af[(dy*4 + c)*64 + lane] : bf16x8
//   elem e of (dy,c,lane): K[dy][16c + 8*(lane>>5) + e - (lane&31)], 0 outside band.
// Size: 31*4*64*16 B = 126976 B in d_ws.
__global__ void build_afrag_kernel(const float* __restrict__ Kf,
                                   unsigned short* __restrict__ af) {
    for (int i = threadIdx.x; i < KH * 4 * 64; i += 256) {
        const int dy = i >> 8;
        const int c  = (i >> 6) & 3;
        const int l  = i & 63;
        const int lr = l & 31, lh = l >> 5;
        unsigned short v[8];
        #pragma unroll
        for (int e = 0; e < 8; ++e) {
            const int idx = 16 * c + 8 * lh + e - lr;
            const float f = (idx >= 0 && idx < KW) ? Kf[dy * KW + idx] : 0.0f;
            v[e] = bf16rne_s(f);
        }
        *reinterpret_cast<bf16x8*>(af + (size_t)i * 8) =
            *reinterpret_cast<bf16x8*>(v);
    }
}

__global__ __launch_bounds__(256, 4)
void conv2d_mfma_bf16(const float* __restrict__ X,
                      const unsigned short* __restrict__ af,
                      float* __restrict__ out) {
    __shared__ unsigned short Xs[SROWS * SPITCH];   // 39680 B
    char* xsb = (char*)Xs;

    const int tid = threadIdx.x;
    const int l   = tid & 63;
    const int lr  = l & 31;       // B col (= y offset) / epilogue y lane
    const int lh  = l >> 5;       // k-half
    const int wv  = tid >> 6;     // 0..3 -> col group
    const int by0 = blockIdx.y * BROWS;
    const int bx0 = blockIdx.x * BCOLS;

    // ---------- stage X tile: fp32 -> bf16, XOR-swizzled ----------
    for (int g = tid; g < SROWS * (SPITCH / 4); g += 256) {
        const int r  = g / (SPITCH / 4);
        const int c0 = (g - r * (SPITCH / 4)) * 4;
        const int gy = by0 + r;
        const int gx = bx0 + c0;
        float4 v = make_float4(0.f, 0.f, 0.f, 0.f);
        if (gy < H) {
            const float* row = X + (size_t)gy * W;
            if (gx + 3 < W) {
                v = *(const float4*)(row + gx);
            } else {
                if (gx + 0 < W) v.x = row[gx + 0];
                if (gx + 1 < W) v.y = row[gx + 1];
                if (gx + 2 < W) v.z = row[gx + 2];
            }
        }
        ushort4 hh;
        hh.x = bf16rne_s(v.x);
        hh.y = bf16rne_s(v.y);
        hh.z = bf16rne_s(v.z);
        hh.w = bf16rne_s(v.w);
        const int byte = r * SPB + c0 * 2;
        *(ushort4*)(xsb + (byte ^ ((r & 7) << 4))) = hh;
    }
    __syncthreads();

    // ---------- main loop: no barriers, LDS read-only ----------
    f32x16 acc[2] = {};
    const int cbase = 64 * wv;                 // wave col offset (elements)
    const bf16x8* A = (const bf16x8*)af;

    for (int dy = 0; dy < KH; ++dy) {
        // A-frags: 4 coalesced 16B loads from the L2-hot table (same for all waves).
        bf16x8 a[4];
        #pragma unroll
        for (int c = 0; c < 4; ++c) a[c] = A[(dy * 4 + c) * 64 + l];

        // B-frags: 6 sliding 16-wide x-chunks; wave-lane rows rr = dy+lr.
        const int rr = dy + lr;                // <= 61
        const int rowbyte = rr * SPB;
        const int swz = (rr & 7) << 4;
        bf16x8 bb[6];
        #pragma unroll
        for (int m = 0; m < 6; ++m) {
            const int byte = rowbyte + (cbase + 16 * m) * 2 + 16 * lh;
            bb[m] = *(const bf16x8*)(xsb + (byte ^ swz));   // ds_read_b128
        }

        // 2 tiles x 4 k-chunks; tile t uses chunks 2t..2t+3.
        #pragma unroll
        for (int t = 0; t < 2; ++t) {
            #pragma unroll
            for (int c = 0; c < 4; ++c) {
                acc[t] = __builtin_amdgcn_mfma_f32_32x32x16_bf16(
                             a[c], bb[2 * t + c], acc[t], 0, 0, 0);
            }
        }
    }

    // ---------- epilogue: D row = x = (reg&3)+8*(reg>>2)+4*lh, col = y = lr ----------
    const int oy = by0 + lr;
    if (oy < OH) {
        float* orow = out + (size_t)oy * OW;
        #pragma unroll
        for (int t = 0; t < 2; ++t) {
            #pragma unroll
            for (int q = 0; q < 4; ++q) {
                const int x = bx0 + cbase + 32 * t + 8 * q + 4 * lh;
                if (x + 3 < OW) {
                    *(float2*)(orow + x)     = make_float2(acc[t][4*q+0], acc[t][4*q+1]);
                    *(float2*)(orow + x + 2) = make_float2(acc[t][4*q+2], acc[t][4*q+3]);
                } else {
                    #pragma unroll
                    for (int e = 0; e < 4; ++e)
                        if (x + e < OW) orow[x + e] = acc[t][4*q+e];
                }
            }
        }
    }
}

extern "C" void kernel_launch(void* const* d_in, const int* in_sizes, int n_in,
                              void* d_out, int out_size, void* d_ws, size_t ws_size,
                              hipStream_t stream) {
    const float* X  = (const float*)d_in[0];
    const float* Kf = (const float*)d_in[1];
    float* out = (float*)d_out;
    unsigned short* af = (unsigned short*)d_ws;   // 126976 B

    build_afrag_kernel<<<1, 256, 0, stream>>>(Kf, af);
    dim3 grid((OW + BCOLS - 1) / BCOLS, (OH + BROWS - 1) / BROWS);  // 16 x 128
    conv2d_mfma_bf16<<<grid, dim3(256), 0, stream>>>(X, af, out);
}